// Round 9
// baseline (499.290 us; speedup 1.0000x reference)
//
#include <hip/hip_runtime.h>
#include <stdint.h>

#define M_DIM 8192
#define K_DIM 4096
#define N_DIM 12288

typedef int v4i __attribute__((ext_vector_type(4)));

#define GLDS16(g, l)                                                         \
  __builtin_amdgcn_global_load_lds(                                          \
      (const __attribute__((address_space(1))) void*)(g),                    \
      (__attribute__((address_space(3))) void*)(l), 16, 0, 0)

#define BARRIER() asm volatile("s_barrier" ::: "memory")
#define VMCNT0() asm volatile("s_waitcnt vmcnt(0)" ::: "memory")

// ---------------------------------------------------------------------------
// Fused prep.
// blocks [0, M): per-token dynamic int8 quant of x (row-major xq).
// blocks [M, M+3072): pack int32-carried W into MFMA-fragment layout:
//   w8p[n_blk][k_blk][kq][fr][16B]  (n_blk=n>>4, k_blk=k>>6, kq=(k>>4)&3,
//   fr=n&15) -> a B-fragment register load in the GEMM is one coalesced
//   global_load_dwordx4 (wave-uniform base + lane*16).
// r9 fix: grid was 768 pack blocks (1/4 coverage, rest poison); each thread
// packs one 64B chunk so packBlocks = N*K/(256*64) = 3072.
// ---------------------------------------------------------------------------
__global__ __launch_bounds__(256) void prep(const float* __restrict__ x,
                                            int8_t* __restrict__ xq,
                                            float* __restrict__ xs,
                                            const int* __restrict__ w32,
                                            int8_t* __restrict__ w8p) {
  const int t = threadIdx.x;
  if ((int)blockIdx.x < M_DIM) {
    const int row = blockIdx.x;
    const float* xr = x + (size_t)row * K_DIM;

    float4 v[4];
    float amax = 0.f;
#pragma unroll
    for (int i = 0; i < 4; ++i) {
      v[i] = reinterpret_cast<const float4*>(xr)[t * 4 + i];
      amax = fmaxf(amax, fmaxf(fmaxf(fabsf(v[i].x), fabsf(v[i].y)),
                               fmaxf(fabsf(v[i].z), fabsf(v[i].w))));
    }
#pragma unroll
    for (int off = 32; off > 0; off >>= 1)
      amax = fmaxf(amax, __shfl_xor(amax, off));

    __shared__ float smax[4];
    if ((t & 63) == 0) smax[t >> 6] = amax;
    __syncthreads();
    amax = fmaxf(fmaxf(smax[0], smax[1]), fmaxf(smax[2], smax[3]));

    const float scale = fmaxf(amax, 1e-8f) / 127.f;

    union {
      int8_t b[16];
      v4i v;
    } p;
    const float* pv = reinterpret_cast<const float*>(v);
#pragma unroll
    for (int i = 0; i < 16; ++i) {
      float r = rintf(pv[i] / scale);  // round-half-to-even == jnp.round
      r = fminf(127.f, fmaxf(-127.f, r));
      p.b[i] = (int8_t)(int)r;
    }
    reinterpret_cast<v4i*>(xq + (size_t)row * K_DIM)[t] = p.v;
    if (t == 0) xs[row] = scale;
  } else {
    // i indexes 64B output chunks: i = nblk*1024 + kblk*16 + kq*4 + frq
    const int i = ((int)blockIdx.x - M_DIM) * 256 + t;  // [0, 786432)
    const int nblk = i >> 10;
    const int kblk = (i >> 4) & 63;
    const int kq = (i >> 2) & 3;
    const int frq = i & 3;
    const int n0 = nblk * 16 + frq * 4;
    const int k0 = kblk * 64 + kq * 16;
    const int* src = w32 + (size_t)n0 * K_DIM + k0;
    int8_t* dst = w8p + (size_t)i * 64;
#pragma unroll
    for (int r = 0; r < 4; ++r) {
      union {
        int8_t b[16];
        v4i v;
      } p;
      const int4* s4 = (const int4*)(src + (size_t)r * K_DIM);
#pragma unroll
      for (int c = 0; c < 4; ++c) {
        int4 q = s4[c];
        p.b[c * 4 + 0] = (int8_t)q.x;
        p.b[c * 4 + 1] = (int8_t)q.y;
        p.b[c * 4 + 2] = (int8_t)q.z;
        p.b[c * 4 + 3] = (int8_t)q.w;
      }
      *(v4i*)(dst + r * 16) = p.v;
    }
  }
}

// ---------------------------------------------------------------------------
// int8 GEMM, 256x256 tile, BK=128B, 8 waves (2Mx4N), 16x16x64 MFMA.
// B comes straight from global (fragment-packed w8p) into registers -- no B
// in LDS. LDS = A only (2 x 32KB double-buffer). A path (staging + XOR
// swizzle + reads) byte-identical to r7 (measured 0 bank conflicts). One
// vmcnt(0)+barrier per K-tile. launch_bounds (512,2): occupancy is
// VGPR-bound (~190 combined regs), not LDS-bound -- (512,4) would spill.
// ---------------------------------------------------------------------------
#define BM 256
#define BN 256
#define BKB 128                 // K bytes per tile
#define NTILES (K_DIM / BKB)    // 32

__global__ __launch_bounds__(512, 2) void gemm_i8(
    const int8_t* __restrict__ xq, const float* __restrict__ xs,
    const int8_t* __restrict__ w8p, const float* __restrict__ wsc,
    const float* __restrict__ bias, float* __restrict__ out) {
  // LDS: A buffers only, buf c at c*32768 (256 rows x 128B each).
  __shared__ __align__(16) int8_t lds[65536];

  const int t = threadIdx.x;
  const int lane = t & 63;
  const int w = t >> 6;      // wave 0..7
  const int wr = w >> 2;     // 0..1 -> 128-row block
  const int wc = w & 3;      // 0..3 -> 64-col block
  const int fr = lane & 15;
  const int kq = lane >> 4;  // 0..3
  const int l7 = lane & 7;

  // 2D XCD swizzle: XCD x owns M-tiles [4x,4x+4); 4M x 8N windows.
  const int bid = (int)blockIdx.x;
  const int xcd = bid & 7;
  const int q = bid >> 3;    // [0,192)
  const int g = q >> 5;      // [0,6)
  const int j = q & 31;
  const int rowBase = (xcd * 4 + (j >> 3)) * BM;
  const int colBase = (g * 8 + (j & 7)) * BN;

  // ---- A staging: thread t -> row t>>3, slot t&7, inverse swizzle on the
  // global source so lds(R,S) = chunk S ^ (R&7).
  const int srow = t >> 3;
  const int gslot = (t & 7) ^ (srow & 7);
  const int8_t* gA = xq + (size_t)(rowBase + srow) * K_DIM + gslot * 16;
  int8_t* ldsw = lds + w * 1024;  // wave-uniform dest base (HW adds lane*16)

#define STAGE_A(c, r0, k0) \
  GLDS16(gA + (size_t)(r0) * K_DIM + (k0), ldsw + (c) * 32768 + (r0) * 128)
#define STAGE_A4(c, k0)                                                       \
  STAGE_A(c, 0, k0); STAGE_A(c, 64, k0);                                      \
  STAGE_A(c, 128, k0); STAGE_A(c, 192, k0);

  // ---- A fragment reads: slot = (ks*4+kq) ^ l7.
  const int s0_ = kq ^ l7;        // ks=0
  const int s1_ = s0_ ^ 4;        // ks=1
  const int rA = wr * 128 + fr;   // + mh*64 + mi*16

  const v4i* pA0 = (const v4i*)lds + ((rA << 3) + s0_);
  const v4i* pA1 = (const v4i*)lds + ((rA << 3) + s1_);

#define LDA(dst, c, mh, ks)                                                   \
  {                                                                           \
    const v4i* _p = (ks) ? pA1 : pA0;                                         \
    dst[0] = _p[((c) << 11) + (((mh) * 64 + 0) << 3)];                        \
    dst[1] = _p[((c) << 11) + (((mh) * 64 + 16) << 3)];                       \
    dst[2] = _p[((c) << 11) + (((mh) * 64 + 32) << 3)];                       \
    dst[3] = _p[((c) << 11) + (((mh) * 64 + 48) << 3)];                       \
  }

  // ---- B fragment loads from packed global. Lane L of fragment (ni,ks)
  // receives w8p[nblkBase+ni][k1/64+ks][L>>4][L&15] == the bytes the r7 LDS
  // read delivered. Base is wave-uniform + lane*16.
  const int nblkBase = (colBase >> 4) + wc * 4;
  const int8_t* gB = w8p + (size_t)nblkBase * 65536 + (size_t)lane * 16;

#define LDB8(bn, k1)                                                          \
  bn[0][0] = *(const v4i*)(gB + (size_t)(k1) * 16 + 0 * 65536);               \
  bn[0][1] = *(const v4i*)(gB + (size_t)(k1) * 16 + 1 * 65536);               \
  bn[0][2] = *(const v4i*)(gB + (size_t)(k1) * 16 + 2 * 65536);               \
  bn[0][3] = *(const v4i*)(gB + (size_t)(k1) * 16 + 3 * 65536);               \
  bn[1][0] = *(const v4i*)(gB + (size_t)(k1) * 16 + 1024 + 0 * 65536);        \
  bn[1][1] = *(const v4i*)(gB + (size_t)(k1) * 16 + 1024 + 1 * 65536);        \
  bn[1][2] = *(const v4i*)(gB + (size_t)(k1) * 16 + 1024 + 2 * 65536);        \
  bn[1][3] = *(const v4i*)(gB + (size_t)(k1) * 16 + 1024 + 3 * 65536);

#define MFMA_BLK(MH, A_, Bv)                                                  \
  __builtin_amdgcn_s_setprio(1);                                              \
  _Pragma("unroll") for (int ni = 0; ni < 4; ++ni)                            \
      _Pragma("unroll") for (int mi = 0; mi < 4; ++mi)                        \
          acc[(MH) * 4 + mi][ni] = __builtin_amdgcn_mfma_i32_16x16x64_i8(     \
              A_[mi], Bv[ni], acc[(MH) * 4 + mi][ni], 0, 0, 0);               \
  __builtin_amdgcn_s_setprio(0);

  v4i acc[8][4];
#pragma unroll
  for (int i = 0; i < 8; ++i)
#pragma unroll
    for (int jj = 0; jj < 4; ++jj) acc[i][jj] = (v4i){0, 0, 0, 0};

  v4i a0[4], a1[4];
  v4i bA[2][4], bB[2][4];  // ping-pong B fragment sets [ks][ni]

  // One K-tile: stage next A + load next B at top; 4 MFMA blocks; single
  // vmcnt(0)+barrier; prefetch next tile's first A set.
#define TILE(c, d, k1, bc, bn)                                                \
  STAGE_A4(d, k1);                                                            \
  LDB8(bn, k1);                                                               \
  LDA(a1, c, 1, 0);                                                           \
  MFMA_BLK(0, a0, bc[0]);                                                     \
  LDA(a0, c, 0, 1);                                                           \
  MFMA_BLK(1, a1, bc[0]);                                                     \
  LDA(a1, c, 1, 1);                                                           \
  MFMA_BLK(0, a0, bc[1]);                                                     \
  MFMA_BLK(1, a1, bc[1]);                                                     \
  VMCNT0();                                                                   \
  BARRIER();                                                                  \
  LDA(a0, d, 0, 0);

#define TILE_LAST(c, bc)                                                      \
  LDA(a1, c, 1, 0);                                                           \
  MFMA_BLK(0, a0, bc[0]);                                                     \
  LDA(a0, c, 0, 1);                                                           \
  MFMA_BLK(1, a1, bc[0]);                                                     \
  LDA(a1, c, 1, 1);                                                           \
  MFMA_BLK(0, a0, bc[1]);                                                     \
  MFMA_BLK(1, a1, bc[1]);

  // prologue: tile0 A -> buf0, tile0 B -> bA; drain; first A fragment set.
  STAGE_A4(0, 0);
  LDB8(bA, 0);
  VMCNT0();
  BARRIER();
  LDA(a0, 0, 0, 0);

  for (int tt = 0; tt < NTILES - 2; tt += 2) {  // tiles 0..29
    TILE(0, 1, (tt + 1) * BKB, bA, bB);
    TILE(1, 0, (tt + 2) * BKB, bB, bA);
  }
  TILE(0, 1, (NTILES - 1) * BKB, bA, bB);  // tile 30, stages tile 31
  TILE_LAST(1, bB);                        // tile 31

  // epilogue: C/D layout col = lane&15, row = (lane>>4)*4 + reg
  const int orow0 = rowBase + wr * 128;
  const int ocol0 = colBase + wc * 64;
  const int rsub = kq * 4;
#pragma unroll
  for (int mi8 = 0; mi8 < 8; ++mi8) {
    const int r0 = orow0 + mi8 * 16 + rsub;
    float s4[4];
#pragma unroll
    for (int r = 0; r < 4; ++r) s4[r] = xs[r0 + r];
#pragma unroll
    for (int ni = 0; ni < 4; ++ni) {
      const int col = ocol0 + ni * 16 + fr;
      const float wf = wsc[col];
      const float bb = bias[col];
#pragma unroll
      for (int r = 0; r < 4; ++r)
        out[(size_t)(r0 + r) * N_DIM + col] =
            (float)acc[mi8][ni][r] * s4[r] * wf + bb;
    }
  }
}

// ---------------------------------------------------------------------------
extern "C" void kernel_launch(void* const* d_in, const int* in_sizes, int n_in,
                              void* d_out, int out_size, void* d_ws,
                              size_t ws_size, hipStream_t stream) {
  const float* x = (const float*)d_in[0];
  const int* w32 = (const int*)d_in[1];
  const float* wscale = (const float*)d_in[2];
  const float* bias = (const float*)d_in[3];
  float* out = (float*)d_out;

  int8_t* xq = (int8_t*)d_ws;
  float* xs = (float*)((char*)d_ws + (size_t)M_DIM * K_DIM);
  int8_t* w8p = (int8_t*)((char*)d_ws + (size_t)M_DIM * K_DIM + M_DIM * 4);

  const int packBlocks = (N_DIM * K_DIM) / (256 * 64);  // 3072 (64B/thread)
  prep<<<M_DIM + packBlocks, 256, 0, stream>>>(x, xq, xs, w32, w8p);
  gemm_i8<<<(M_DIM / BM) * (N_DIM / BN), 512, 0, stream>>>(xq, xs, w8p, wscale,
                                                           bias, out);
}

// Round 13
// 461.221 us; speedup vs baseline: 1.0825x; 1.0825x over previous
//
#include <hip/hip_runtime.h>
#include <stdint.h>

#define M_DIM 8192
#define K_DIM 4096
#define N_DIM 12288

typedef int v4i __attribute__((ext_vector_type(4)));

#define GLDS16(g, l)                                                         \
  __builtin_amdgcn_global_load_lds(                                          \
      (const __attribute__((address_space(1))) void*)(g),                    \
      (__attribute__((address_space(3))) void*)(l), 16, 0, 0)

#define BARRIER() asm volatile("s_barrier" ::: "memory")
#define VMCNT0() asm volatile("s_waitcnt vmcnt(0)" ::: "memory")

// ---------------------------------------------------------------------------
// Fused prep: blocks [0, M) quantize x rows; blocks [M, M+12288) pack weights
// row-major int8 (r7-proven path).
// ---------------------------------------------------------------------------
__global__ __launch_bounds__(256) void prep(const float* __restrict__ x,
                                            int8_t* __restrict__ xq,
                                            float* __restrict__ xs,
                                            const int* __restrict__ w32,
                                            int8_t* __restrict__ w8) {
  const int t = threadIdx.x;
  if ((int)blockIdx.x < M_DIM) {
    const int row = blockIdx.x;
    const float* xr = x + (size_t)row * K_DIM;

    float4 v[4];
    float amax = 0.f;
#pragma unroll
    for (int i = 0; i < 4; ++i) {
      v[i] = reinterpret_cast<const float4*>(xr)[t * 4 + i];
      amax = fmaxf(amax, fmaxf(fmaxf(fabsf(v[i].x), fabsf(v[i].y)),
                               fmaxf(fabsf(v[i].z), fabsf(v[i].w))));
    }
#pragma unroll
    for (int off = 32; off > 0; off >>= 1)
      amax = fmaxf(amax, __shfl_xor(amax, off));

    __shared__ float smax[4];
    if ((t & 63) == 0) smax[t >> 6] = amax;
    __syncthreads();
    amax = fmaxf(fmaxf(smax[0], smax[1]), fmaxf(smax[2], smax[3]));

    const float scale = fmaxf(amax, 1e-8f) / 127.f;

    union {
      int8_t b[16];
      v4i v;
    } p;
    const float* pv = reinterpret_cast<const float*>(v);
#pragma unroll
    for (int i = 0; i < 16; ++i) {
      float r = rintf(pv[i] / scale);  // round-half-to-even == jnp.round
      r = fminf(127.f, fmaxf(-127.f, r));
      p.b[i] = (int8_t)(int)r;
    }
    reinterpret_cast<v4i*>(xq + (size_t)row * K_DIM)[t] = p.v;
    if (t == 0) xs[row] = scale;
  } else {
    const size_t i = (((size_t)blockIdx.x - M_DIM) * 256 + t) * 16;
    const int4* src = reinterpret_cast<const int4*>(w32 + i);
    union {
      int8_t b[16];
      v4i v;
    } p;
#pragma unroll
    for (int c = 0; c < 4; ++c) {
      int4 q = src[c];
      p.b[c * 4 + 0] = (int8_t)q.x;
      p.b[c * 4 + 1] = (int8_t)q.y;
      p.b[c * 4 + 2] = (int8_t)q.z;
      p.b[c * 4 + 3] = (int8_t)q.w;
    }
    *reinterpret_cast<v4i*>(w8 + i) = p.v;
  }
}

// ---------------------------------------------------------------------------
// int8 GEMM (r7-proven best: 381 us, MfmaUtil 50%, 0 bank conflicts).
// 256x256 tile, BK=128B, 8 waves (2Mx4N), 16x16x64 MFMA.
// ONE barrier + ONE vmcnt(0) per K-tile; full LDS double-buffer; A+B staged
// via global_load_lds with XOR-swizzled global source; fragment reads are
// single ds_read_b128 base+imm via precomputed per-thread base pointers.
// r10-r13 delta vs r7: epilogue xs loads vectorized to float4.
// ---------------------------------------------------------------------------
#define BM 256
#define BN 256
#define BKB 128                 // K bytes per tile
#define NTILES (K_DIM / BKB)    // 32

__global__ __launch_bounds__(512, 2) void gemm_i8(
    const int8_t* __restrict__ xq, const float* __restrict__ xs,
    const int8_t* __restrict__ w8, const float* __restrict__ wsc,
    const float* __restrict__ bias, float* __restrict__ out) {
  // LDS map: A bufs at c*32768 (256 rows x 128B), B bufs at 65536 + c*32768.
  __shared__ __align__(16) int8_t lds[131072];

  const int t = threadIdx.x;
  const int lane = t & 63;
  const int w = t >> 6;      // wave 0..7
  const int wr = w >> 2;     // 0..1 -> 128-row block
  const int wc = w & 3;      // 0..3 -> 64-col block
  const int fr = lane & 15;
  const int kq = lane >> 4;  // 0..3
  const int l7 = lane & 7;

  // 2D XCD swizzle: XCD x owns M-tiles [4x,4x+4); 4M x 8N windows
  // (bijective: 8 xcd * 6 g * 32 j = 1536).
  const int bid = (int)blockIdx.x;
  const int xcd = bid & 7;
  const int q = bid >> 3;    // [0,192)
  const int g = q >> 5;      // [0,6)
  const int j = q & 31;
  const int rowBase = (xcd * 4 + (j >> 3)) * BM;
  const int colBase = (g * 8 + (j & 7)) * BN;

  // staging: thread t -> row srow = t>>3, lds 16B-slot t&7; inverse swizzle on
  // the GLOBAL source so lds(R,S) holds global chunk S ^ (R&7).
  const int srow = t >> 3;
  const int gslot = (t & 7) ^ (srow & 7);
  const int8_t* gA = xq + (size_t)(rowBase + srow) * K_DIM + gslot * 16;
  const int8_t* gB = w8 + (size_t)(colBase + srow) * K_DIM + gslot * 16;
  int8_t* ldsw = lds + w * 1024;  // wave-uniform dest base (HW adds lane*16)

#define STAGE_A(c, r0, k0) \
  GLDS16(gA + (size_t)(r0) * K_DIM + (k0), ldsw + (c) * 32768 + (r0) * 128)
#define STAGE_B(c, r0, k0) \
  GLDS16(gB + (size_t)(r0) * K_DIM + (k0), ldsw + 65536 + (c) * 32768 + (r0) * 128)

#define STAGE8(d, k1)                                                         \
  STAGE_B(d, 0, k1); STAGE_B(d, 64, k1);                                      \
  STAGE_B(d, 128, k1); STAGE_B(d, 192, k1);                                   \
  STAGE_A(d, 0, k1); STAGE_A(d, 64, k1);                                      \
  STAGE_A(d, 128, k1); STAGE_A(d, 192, k1);

  // fragment read slot: (ks*4 + kq) ^ (row&7); row&7 == l7 (bases mult-16).
  const int s0_ = kq ^ l7;        // ks=0
  const int s1_ = s0_ ^ 4;        // ks=1
  const int rA = wr * 128 + fr;   // + mh*64 + mi*16
  const int rB = wc * 64 + fr;    // + ni*16

  // Precomputed per-thread LDS base pointers; every fragment read is a single
  // ds_read_b128 with a 16-bit immediate (max imm 47104 < 65536).
  const v4i* pA0 = (const v4i*)lds + ((rA << 3) + s0_);
  const v4i* pA1 = (const v4i*)lds + ((rA << 3) + s1_);
  const v4i* pB0 = (const v4i*)(lds + 65536) + ((rB << 3) + s0_);
  const v4i* pB1 = (const v4i*)(lds + 65536) + ((rB << 3) + s1_);

#define LDA(dst, c, mh, ks)                                                   \
  {                                                                           \
    const v4i* _p = (ks) ? pA1 : pA0;                                         \
    dst[0] = _p[((c) << 11) + (((mh) * 64 + 0) << 3)];                        \
    dst[1] = _p[((c) << 11) + (((mh) * 64 + 16) << 3)];                       \
    dst[2] = _p[((c) << 11) + (((mh) * 64 + 32) << 3)];                       \
    dst[3] = _p[((c) << 11) + (((mh) * 64 + 48) << 3)];                       \
  }
#define LDB(dst, c, ks)                                                       \
  {                                                                           \
    const v4i* _p = (ks) ? pB1 : pB0;                                         \
    dst[0] = _p[((c) << 11) + (0 << 3)];                                      \
    dst[1] = _p[((c) << 11) + (16 << 3)];                                     \
    dst[2] = _p[((c) << 11) + (32 << 3)];                                     \
    dst[3] = _p[((c) << 11) + (48 << 3)];                                     \
  }

#define MFMA_BLK(MH, A_, B_)                                                  \
  __builtin_amdgcn_s_setprio(1);                                              \
  _Pragma("unroll") for (int ni = 0; ni < 4; ++ni)                            \
      _Pragma("unroll") for (int mi = 0; mi < 4; ++mi)                        \
          acc[(MH) * 4 + mi][ni] = __builtin_amdgcn_mfma_i32_16x16x64_i8(     \
              A_[mi], B_[ni], acc[(MH) * 4 + mi][ni], 0, 0, 0);               \
  __builtin_amdgcn_s_setprio(0);

  v4i acc[8][4];
#pragma unroll
  for (int i = 0; i < 8; ++i)
#pragma unroll
    for (int jj = 0; jj < 4; ++jj) acc[i][jj] = (v4i){0, 0, 0, 0};

  v4i a0[4], a1[4], b0[4], b1[4];

  // One K-tile: stage next tile at top, 4 software-pipelined MFMA blocks,
  // single vmcnt+barrier at end, then prefetch next tile's first fragments.
#define TILE(c, d, k1)                                                        \
  STAGE8(d, k1);                                                              \
  LDA(a1, c, 1, 0);                                                           \
  MFMA_BLK(0, a0, b0);                                                        \
  LDA(a0, c, 0, 1);                                                           \
  LDB(b1, c, 1);                                                              \
  MFMA_BLK(1, a1, b0);                                                        \
  LDA(a1, c, 1, 1);                                                           \
  MFMA_BLK(0, a0, b1);                                                        \
  MFMA_BLK(1, a1, b1);                                                        \
  VMCNT0();                                                                   \
  BARRIER();                                                                  \
  LDA(a0, d, 0, 0);                                                           \
  LDB(b0, d, 0);

#define TILE_LAST(c)                                                          \
  LDA(a1, c, 1, 0);                                                           \
  MFMA_BLK(0, a0, b0);                                                        \
  LDA(a0, c, 0, 1);                                                           \
  LDB(b1, c, 1);                                                              \
  MFMA_BLK(1, a1, b0);                                                        \
  LDA(a1, c, 1, 1);                                                           \
  MFMA_BLK(0, a0, b1);                                                        \
  MFMA_BLK(1, a1, b1);

  // prologue: tile0 -> buf0; drain; load tile0's first fragment sets.
  STAGE8(0, 0);
  VMCNT0();
  BARRIER();
  LDA(a0, 0, 0, 0);
  LDB(b0, 0, 0);

  for (int tt = 0; tt < NTILES - 2; tt += 2) {  // tiles 0..29
    TILE(0, 1, (tt + 1) * BKB);
    TILE(1, 0, (tt + 2) * BKB);
  }
  TILE(0, 1, (NTILES - 1) * BKB);  // tile 30, stages tile 31
  TILE_LAST(1);                    // tile 31

  // epilogue: C/D layout col = lane&15, row = (lane>>4)*4 + reg
  const int orow0 = rowBase + wr * 128;
  const int ocol0 = colBase + wc * 64;
  const int rsub = kq * 4;
#pragma unroll
  for (int mi8 = 0; mi8 < 8; ++mi8) {
    const int r0 = orow0 + mi8 * 16 + rsub;  // multiple of 4 -> float4 load
    const float4 s4v = *reinterpret_cast<const float4*>(xs + r0);
    const float s4[4] = {s4v.x, s4v.y, s4v.z, s4v.w};
#pragma unroll
    for (int ni = 0; ni < 4; ++ni) {
      const int col = ocol0 + ni * 16 + fr;
      const float wf = wsc[col];
      const float bb = bias[col];
#pragma unroll
      for (int r = 0; r < 4; ++r)
        out[(size_t)(r0 + r) * N_DIM + col] =
            (float)acc[mi8][ni][r] * s4[r] * wf + bb;
    }
  }
}

// ---------------------------------------------------------------------------
extern "C" void kernel_launch(void* const* d_in, const int* in_sizes, int n_in,
                              void* d_out, int out_size, void* d_ws,
                              size_t ws_size, hipStream_t stream) {
  const float* x = (const float*)d_in[0];
  const int* w32 = (const int*)d_in[1];
  const float* wscale = (const float*)d_in[2];
  const float* bias = (const float*)d_in[3];
  float* out = (float*)d_out;

  int8_t* xq = (int8_t*)d_ws;
  float* xs = (float*)((char*)d_ws + (size_t)M_DIM * K_DIM);
  int8_t* w8 = (int8_t*)((char*)d_ws + (size_t)M_DIM * K_DIM + M_DIM * 4);

  const int packBlocks = (N_DIM * K_DIM) / (256 * 16);  // 12288
  prep<<<M_DIM + packBlocks, 256, 0, stream>>>(x, xq, xs, w32, w8);
  gemm_i8<<<(M_DIM / BM) * (N_DIM / BN), 512, 0, stream>>>(xq, xs, w8, wscale,
                                                           bias, out);
}